// Round 9
// baseline (392.418 us; speedup 1.0000x reference)
//
#include <hip/hip_runtime.h>
#include <hip/hip_bf16.h>

#define N_NODES 50000
#define N_EDGES 625000
#define IN_DIM  300
#define KPAD    320   // IN_DIM padded to multiple of 32
#define HID     128
#define NLAYERS 4

#define SB      256                            // scan block size
#define NCH     ((N_NODES + SB - 1) / SB)      // 196 chunks

typedef __hip_bfloat16 bf16;
typedef __attribute__((ext_vector_type(8))) short short8;   // 8 bf16 = 4 VGPRs
typedef __attribute__((ext_vector_type(4))) float f32x4;

__device__ inline short f2bf(float v) {
    bf16 t = __float2bfloat16(v);
    return *reinterpret_cast<short*>(&t);
}
__device__ inline unsigned short f2bfu(float v) {
    bf16 t = __float2bfloat16(v);
    return *reinterpret_cast<unsigned short*>(&t);
}
__device__ inline float bflo(unsigned v) { return __uint_as_float((v & 0xffffu) << 16); }
__device__ inline float bfhi(unsigned v) { return __uint_as_float(v & 0xffff0000u); }

// ---------------- degree histogram (int) ----------------
__global__ void k_deg(const int* __restrict__ dst, int* __restrict__ deg) {
    int e = blockIdx.x * blockDim.x + threadIdx.x;
    if (e < N_EDGES) atomicAdd(&deg[dst[e]], 1);
}

// ---------------- hierarchical scan: deg -> exclusive prefix ----------------
__global__ void k_scan1(const int* __restrict__ deg, int* __restrict__ bsum) {
    const int i = blockIdx.x * SB + threadIdx.x;
    int v = (i < N_NODES) ? deg[i] : 0;
#pragma unroll
    for (int off = 32; off > 0; off >>= 1) v += __shfl_down(v, off);
    __shared__ int wsum[SB / 64];
    if ((threadIdx.x & 63) == 0) wsum[threadIdx.x >> 6] = v;
    __syncthreads();
    if (threadIdx.x == 0) {
        int s = 0;
#pragma unroll
        for (int w = 0; w < SB / 64; w++) s += wsum[w];
        bsum[blockIdx.x] = s;
    }
}

__global__ void k_scan2(const int* __restrict__ bsum, int* __restrict__ boff) {
    __shared__ int s[SB];
    const int t = threadIdx.x;
    int v = (t < NCH) ? bsum[t] : 0;
    s[t] = v;
    __syncthreads();
    for (int off = 1; off < SB; off <<= 1) {
        int u = (t >= off) ? s[t - off] : 0;
        __syncthreads();
        s[t] += u;
        __syncthreads();
    }
    if (t < NCH) boff[t] = s[t] - v;   // exclusive
}

__global__ void k_scan3(const int* __restrict__ deg, const int* __restrict__ boff,
                        int* __restrict__ rowcur) {
    __shared__ int s[SB];
    const int b = blockIdx.x, t = threadIdx.x;
    const int i = b * SB + t;
    int v = (i < N_NODES) ? deg[i] : 0;
    s[t] = v;
    __syncthreads();
    for (int off = 1; off < SB; off <<= 1) {
        int u = (t >= off) ? s[t - off] : 0;
        __syncthreads();
        s[t] += u;
        __syncthreads();
    }
    if (i < N_NODES) rowcur[i] = boff[b] + s[t] - v;   // exclusive
}

// ---------------- deg(int) -> 1/max(deg,1) (float, in place) ----------------
__global__ void k_invdeg(int* degbuf) {
    int i = blockIdx.x * blockDim.x + threadIdx.x;
    if (i < N_NODES) {
        int d = degbuf[i];
        float inv = 1.0f / (float)max(d, 1);
        ((float*)degbuf)[i] = inv;
    }
}

// ---------------- CSR fill ----------------
__global__ void k_fill(const int* __restrict__ src, const int* __restrict__ dst,
                       int* __restrict__ rowcur, int* __restrict__ csr_src) {
    int e = blockIdx.x * blockDim.x + threadIdx.x;
    if (e < N_EDGES) {
        int d = dst[e];
        int pos = atomicAdd(&rowcur[d], 1);
        csr_src[pos] = src[e];
    }
}

// ---------------- Wl/Wr -> W^T bf16 ----------------
__global__ void k_wconv(const float* __restrict__ Wl, const float* __restrict__ Wr,
                        bf16* __restrict__ WlT, bf16* __restrict__ WrT) {
    int idx = blockIdx.x * 256 + threadIdx.x;
    if (idx >= NLAYERS * HID * HID) return;
    int l = idx / (HID * HID);
    int rem = idx - l * HID * HID;
    int k = rem >> 7;
    int f = rem & 127;
    size_t o = (size_t)l * HID * HID + (size_t)f * HID + k;
    WlT[o] = __float2bfloat16(Wl[idx]);
    WrT[o] = __float2bfloat16(Wr[idx]);
}

// ---------------- emb_W[300][128] -> embT[128][KPAD] bf16 (zero-padded K) ----------------
__global__ void k_wembT(const float* __restrict__ W, bf16* __restrict__ embT) {
    int idx = blockIdx.x * 256 + threadIdx.x;
    if (idx >= HID * KPAD) return;
    int f = idx / KPAD, k = idx - f * KPAD;
    float v = (k < IN_DIM) ? W[(size_t)k * HID + f] : 0.0f;
    embT[idx] = __float2bfloat16(v);
}

// ---------------- embedding via MFMA, 2-phase hoisted x-loads ----------------
// block = 4 waves x 16 rows = 64 rows; grid 782. __launch_bounds__(256,4) -> VGPR cap ~128
__global__ __launch_bounds__(256, 4)
void k_embed_mfma(const float* __restrict__ x, const bf16* __restrict__ embT,
                  const float* __restrict__ b, bf16* __restrict__ h) {
    const int wid  = threadIdx.x >> 6;
    const int lane = threadIdx.x & 63;
    const int r0   = blockIdx.x * 64 + wid * 16;
    const int lrow = lane & 15;
    const int kgrp = lane >> 4;

    const int arow = min(r0 + lrow, N_NODES - 1);
    const float* xrow = x + (size_t)arow * IN_DIM;

    f32x4 acc[8];
#pragma unroll
    for (int c = 0; c < 8; c++) acc[c] = (f32x4){0.f, 0.f, 0.f, 0.f};

    // ---- phase 0: kk = 0..4 (all full; max k = 4*32+24+8 = 160 < 300) ----
    {
        float4 xa[5], xb[5];
#pragma unroll
        for (int kk = 0; kk < 5; kk++) {
            const int k0 = kk * 32 + kgrp * 8;
            xa[kk] = *reinterpret_cast<const float4*>(xrow + k0);
            xb[kk] = *reinterpret_cast<const float4*>(xrow + k0 + 4);
        }
#pragma unroll
        for (int kk = 0; kk < 5; kk++) {
            const int k0 = kk * 32 + kgrp * 8;
            short8 a;
            a[0] = f2bf(xa[kk].x); a[1] = f2bf(xa[kk].y); a[2] = f2bf(xa[kk].z); a[3] = f2bf(xa[kk].w);
            a[4] = f2bf(xb[kk].x); a[5] = f2bf(xb[kk].y); a[6] = f2bf(xb[kk].z); a[7] = f2bf(xb[kk].w);
#pragma unroll
            for (int c = 0; c < 8; c++) {
                short8 bfrag = *reinterpret_cast<const short8*>(embT + (size_t)(c * 16 + lrow) * KPAD + k0);
                acc[c] = __builtin_amdgcn_mfma_f32_16x16x32_bf16(a, bfrag, acc[c], 0, 0, 0);
            }
        }
    }
    // ---- phase 1: kk = 5..8 full, kk = 9 masked tail ----
    {
        float4 xa[4], xb[4];
#pragma unroll
        for (int kk = 5; kk < 9; kk++) {       // max k = 8*32+24+8 = 288 <= 300-8? 280+8=288<300 ok... (kgrp=3,kk=8: 256+24=280, +8 floats -> 288 <= 300)
            const int k0 = kk * 32 + kgrp * 8;
            xa[kk - 5] = *reinterpret_cast<const float4*>(xrow + k0);
            xb[kk - 5] = *reinterpret_cast<const float4*>(xrow + k0 + 4);
        }
        float xt[8];
        {
            const int k0 = 288 + kgrp * 8;
#pragma unroll
            for (int j = 0; j < 8; j++) {
                int k = k0 + j;
                xt[j] = (k < IN_DIM) ? xrow[k] : 0.0f;
            }
        }
#pragma unroll
        for (int kk = 5; kk < 9; kk++) {
            const int k0 = kk * 32 + kgrp * 8;
            short8 a;
            a[0] = f2bf(xa[kk - 5].x); a[1] = f2bf(xa[kk - 5].y); a[2] = f2bf(xa[kk - 5].z); a[3] = f2bf(xa[kk - 5].w);
            a[4] = f2bf(xb[kk - 5].x); a[5] = f2bf(xb[kk - 5].y); a[6] = f2bf(xb[kk - 5].z); a[7] = f2bf(xb[kk - 5].w);
#pragma unroll
            for (int c = 0; c < 8; c++) {
                short8 bfrag = *reinterpret_cast<const short8*>(embT + (size_t)(c * 16 + lrow) * KPAD + k0);
                acc[c] = __builtin_amdgcn_mfma_f32_16x16x32_bf16(a, bfrag, acc[c], 0, 0, 0);
            }
        }
        {   // kk = 9
            const int k0 = 288 + kgrp * 8;
            short8 a;
#pragma unroll
            for (int j = 0; j < 8; j++) a[j] = f2bf(xt[j]);
#pragma unroll
            for (int c = 0; c < 8; c++) {
                short8 bfrag = *reinterpret_cast<const short8*>(embT + (size_t)(c * 16 + lrow) * KPAD + k0);
                acc[c] = __builtin_amdgcn_mfma_f32_16x16x32_bf16(a, bfrag, acc[c], 0, 0, 0);
            }
        }
    }

#pragma unroll
    for (int c = 0; c < 8; c++) {
        const int col = c * 16 + lrow;
        const float bias = b[col];
#pragma unroll
        for (int r = 0; r < 4; r++) {
            const int row = r0 + kgrp * 4 + r;
            if (row < N_NODES)
                h[(size_t)row * HID + col] = __float2bfloat16(fmaxf(acc[c][r] + bias, 0.0f));
        }
    }
}

// ---------------- gather-aggregate: wave-wide index preload + shfl-distributed rows ----
// wave = 1 node. One vector load grabs up to 64 edge indices; row loads take their
// address from __shfl (registers) so all row loads are independent.
__global__ void k_gather(const int* __restrict__ rowend, const int* __restrict__ csr_src,
                         const bf16* __restrict__ h, const float* __restrict__ invdeg,
                         bf16* __restrict__ agg) {
    const int node = blockIdx.x * (blockDim.x >> 6) + (threadIdx.x >> 6);
    if (node >= N_NODES) return;
    const int lane = threadIdx.x & 63;
    const int g    = lane >> 4;
    const int fl   = lane & 15;
    const int beg = (node == 0) ? 0 : rowend[node - 1];
    const int end = rowend[node];
    const int deg = end - beg;

    float a0 = 0.f, a1 = 0.f, a2 = 0.f, a3 = 0.f;
    float a4 = 0.f, a5 = 0.f, a6 = 0.f, a7 = 0.f;
    float c0 = 0.f, c1 = 0.f, c2 = 0.f, c3 = 0.f;
    float c4 = 0.f, c5 = 0.f, c6 = 0.f, c7 = 0.f;

    for (int base = 0; base < deg; base += 64) {
        const int nb = min(deg - base, 64);
        const int sidx = csr_src[beg + base + min(lane, nb - 1)];   // one wave-wide load
        for (int j0 = 0; j0 < nb; j0 += 16) {
#pragma unroll
            for (int u = 0; u < 4; u++) {
                const int j = j0 + u * 4 + g;                        // <= 63 always
                const int s = __shfl(sidx, j);
                if (j < nb) {
                    uint4 v = *reinterpret_cast<const uint4*>(h + (size_t)s * HID + fl * 8);
                    if (u & 1) {
                        c0 += bflo(v.x); c1 += bfhi(v.x); c2 += bflo(v.y); c3 += bfhi(v.y);
                        c4 += bflo(v.z); c5 += bfhi(v.z); c6 += bflo(v.w); c7 += bfhi(v.w);
                    } else {
                        a0 += bflo(v.x); a1 += bfhi(v.x); a2 += bflo(v.y); a3 += bfhi(v.y);
                        a4 += bflo(v.z); a5 += bfhi(v.z); a6 += bflo(v.w); a7 += bfhi(v.w);
                    }
                }
            }
        }
    }
    a0 += c0; a1 += c1; a2 += c2; a3 += c3;
    a4 += c4; a5 += c5; a6 += c6; a7 += c7;

    // reduce across the 4 groups (lanes differing in bits 4,5)
    a0 += __shfl_xor(a0, 16); a1 += __shfl_xor(a1, 16);
    a2 += __shfl_xor(a2, 16); a3 += __shfl_xor(a3, 16);
    a4 += __shfl_xor(a4, 16); a5 += __shfl_xor(a5, 16);
    a6 += __shfl_xor(a6, 16); a7 += __shfl_xor(a7, 16);
    a0 += __shfl_xor(a0, 32); a1 += __shfl_xor(a1, 32);
    a2 += __shfl_xor(a2, 32); a3 += __shfl_xor(a3, 32);
    a4 += __shfl_xor(a4, 32); a5 += __shfl_xor(a5, 32);
    a6 += __shfl_xor(a6, 32); a7 += __shfl_xor(a7, 32);

    if (g == 0) {
        const float id = invdeg[node];
        uint4 o;
        o.x = (unsigned)f2bfu(a0 * id) | ((unsigned)f2bfu(a1 * id) << 16);
        o.y = (unsigned)f2bfu(a2 * id) | ((unsigned)f2bfu(a3 * id) << 16);
        o.z = (unsigned)f2bfu(a4 * id) | ((unsigned)f2bfu(a5 * id) << 16);
        o.w = (unsigned)f2bfu(a6 * id) | ((unsigned)f2bfu(a7 * id) << 16);
        *reinterpret_cast<uint4*>(agg + (size_t)node * HID + fl * 8) = o;
    }
}

// ---------------- combine via MFMA: out = relu(agg @ Wl + bl + h_in @ Wr) ----------------
// h_out may alias agg: each wave reads only its own 16 rows before writing them.
template<int STORE_F32>
__global__ void k_combine_mfma(const bf16* __restrict__ agg, const bf16* __restrict__ h_in,
                               const bf16* __restrict__ WlT, const bf16* __restrict__ WrT,
                               const float* __restrict__ bl, void* __restrict__ outp) {
    const int wid  = threadIdx.x >> 6;
    const int lane = threadIdx.x & 63;
    const int r0   = blockIdx.x * 64 + wid * 16;
    const int lrow = lane & 15;
    const int kgrp = lane >> 4;

    f32x4 acc[8];
#pragma unroll
    for (int c = 0; c < 8; c++) acc[c] = (f32x4){0.f, 0.f, 0.f, 0.f};

    const int arow = min(r0 + lrow, N_NODES - 1);

#pragma unroll
    for (int m = 0; m < 2; m++) {
        const bf16* A  = m ? h_in : agg;
        const bf16* BT = m ? WrT  : WlT;
#pragma unroll
        for (int kk = 0; kk < 4; kk++) {
            const int k0 = kk * 32 + kgrp * 8;
            short8 a = *reinterpret_cast<const short8*>(A + (size_t)arow * HID + k0);
#pragma unroll
            for (int c = 0; c < 8; c++) {
                short8 b = *reinterpret_cast<const short8*>(BT + (size_t)(c * 16 + lrow) * HID + k0);
                acc[c] = __builtin_amdgcn_mfma_f32_16x16x32_bf16(a, b, acc[c], 0, 0, 0);
            }
        }
    }

#pragma unroll
    for (int c = 0; c < 8; c++) {
        const int col = c * 16 + lrow;
        const float bias = bl[col];
#pragma unroll
        for (int r = 0; r < 4; r++) {
            const int row = r0 + kgrp * 4 + r;
            if (row < N_NODES) {
                float v = fmaxf(acc[c][r] + bias, 0.0f);
                if (STORE_F32)
                    ((float*)outp)[(size_t)row * HID + col] = v;
                else
                    ((bf16*)outp)[(size_t)row * HID + col] = __float2bfloat16(v);
            }
        }
    }
}

extern "C" void kernel_launch(void* const* d_in, const int* in_sizes, int n_in,
                              void* d_out, int out_size, void* d_ws, size_t ws_size,
                              hipStream_t stream) {
    const float* x     = (const float*)d_in[0];
    const int*   ei    = (const int*)d_in[1];
    const float* emb_W = (const float*)d_in[2];
    const float* emb_b = (const float*)d_in[3];
    const float* Wl    = (const float*)d_in[4];
    const float* bl    = (const float*)d_in[5];
    const float* Wr    = (const float*)d_in[6];

    const int* src = ei;
    const int* dst = ei + N_EDGES;

    // workspace layout
    char* ws = (char*)d_ws;
    size_t o = 0;
    int*  degbuf = (int*)(ws + o);  o += ((size_t)N_NODES * 4 + 255) & ~(size_t)255;
    int*  rowcur = (int*)(ws + o);  o += ((size_t)N_NODES * 4 + 255) & ~(size_t)255;
    int*  csrsrc = (int*)(ws + o);  o += ((size_t)N_EDGES * 4 + 255) & ~(size_t)255;
    int*  bsum   = (int*)(ws + o);  o += ((size_t)NCH * 4 + 255) & ~(size_t)255;
    int*  boff   = (int*)(ws + o);  o += ((size_t)NCH * 4 + 255) & ~(size_t)255;
    bf16* WlT    = (bf16*)(ws + o); o += ((size_t)NLAYERS * HID * HID * 2 + 255) & ~(size_t)255;
    bf16* WrT    = (bf16*)(ws + o); o += ((size_t)NLAYERS * HID * HID * 2 + 255) & ~(size_t)255;
    bf16* embT   = (bf16*)(ws + o); o += ((size_t)HID * KPAD * 2 + 255) & ~(size_t)255;
    bf16* bufA   = (bf16*)(ws + o); o += ((size_t)N_NODES * HID * 2 + 255) & ~(size_t)255;
    bf16* bufB   = (bf16*)(ws + o);

    // ---- build CSR ----
    hipMemsetAsync(degbuf, 0, (size_t)N_NODES * sizeof(int), stream);
    k_deg<<<(N_EDGES + 255) / 256, 256, 0, stream>>>(dst, degbuf);
    k_scan1<<<NCH, SB, 0, stream>>>(degbuf, bsum);
    k_scan2<<<1, SB, 0, stream>>>(bsum, boff);
    k_scan3<<<NCH, SB, 0, stream>>>(degbuf, boff, rowcur);
    k_invdeg<<<(N_NODES + 255) / 256, 256, 0, stream>>>(degbuf);
    const float* invdeg = (const float*)degbuf;
    k_fill<<<(N_EDGES + 255) / 256, 256, 0, stream>>>(src, dst, rowcur, csrsrc);
    // rowcur[n] is now the END offset of row n

    // ---- weight prep ----
    k_wconv<<<(NLAYERS * HID * HID + 255) / 256, 256, 0, stream>>>(Wl, Wr, WlT, WrT);
    k_wembT<<<(HID * KPAD + 255) / 256, 256, 0, stream>>>(emb_W, embT);

    // ---- h0 = relu(x @ emb_W + emb_b) -> bufA (bf16), via MFMA ----
    const int cgrid = (N_NODES + 63) / 64;   // 782
    k_embed_mfma<<<cgrid, 256, 0, stream>>>(x, embT, emb_b, bufA);

    for (int l = 0; l < NLAYERS; l++) {
        bf16* h_in = (l & 1) ? bufB : bufA;
        bf16* aggb = (l & 1) ? bufA : bufB;
        k_gather<<<(N_NODES + 3) / 4, 256, 0, stream>>>(rowcur, csrsrc, h_in, invdeg, aggb);
        const bf16* wlt = WlT + (size_t)l * HID * HID;
        const bf16* wrt = WrT + (size_t)l * HID * HID;
        const float* blp = bl + (size_t)l * HID;
        if (l == NLAYERS - 1)
            k_combine_mfma<1><<<cgrid, 256, 0, stream>>>(aggb, h_in, wlt, wrt, blp, d_out);
        else
            k_combine_mfma<0><<<cgrid, 256, 0, stream>>>(aggb, h_in, wlt, wrt, blp, aggb);
    }
}